// Round 14
// baseline (303.963 us; speedup 1.0000x reference)
//
#include <hip/hip_runtime.h>
#include <hip/hip_bf16.h>

#define G 5
#define B 8
#define CIN 320
#define CIN_G 64
#define COUT 480
#define COUT_G 96
#define NPOS 15872
#define NSTAT (B*NPOS)
#define BN_EPS 1e-5f
#define KDIM 62
#define SLABBF 31744        // bf16 slots per (b,ch) slab region of d_out

typedef float  f32x4 __attribute__((ext_vector_type(4)));
typedef float  f32x2 __attribute__((ext_vector_type(2)));
typedef __bf16 bf16x8 __attribute__((ext_vector_type(8)));
typedef __bf16 bf16x4 __attribute__((ext_vector_type(4)));

// ---------------- prep: W1,W2 -> bf16; L column sums
__global__ __launch_bounds__(256) void k_prep(
    const float* __restrict__ W1, const float* __restrict__ W2, const float* __restrict__ L,
    __bf16* __restrict__ W1b, __bf16* __restrict__ W2b, float* __restrict__ lcs)
{
    const int bx = blockIdx.x;
    if (bx < 300) {
        const int i = bx * 256 + threadIdx.x;
        if (i < 30720) W1b[i] = (__bf16)W1[i];
        else W2b[i - 30720] = (__bf16)W2[i - 30720];
    } else {
        const int g = bx - 300, p = threadIdx.x;
        if (p < KDIM) {
            float s = 0.f;
            for (int k = 0; k < KDIM; ++k) s += L[(g * KDIM + k) * KDIM + p];
            lcs[g * KDIM + p] = s;
        }
    }
}

// ---------------- BN1 stats pass: conv1 to REGISTERS only (no h store), reduce stats.
__global__ __launch_bounds__(256) void k_stat1(
    const float* __restrict__ x, const __bf16* __restrict__ W1b,
    float* __restrict__ sum1, float* __restrict__ sq1)
{
    __shared__ __bf16 wl[COUT_G * 72];            // 13824 B
    __shared__ float st[COUT_G * 2];
    const int b = blockIdx.z, g = blockIdx.y;
    for (int i = threadIdx.x; i < 768; i += 256) {
        const int idx = i * 8, o = idx >> 6, c = idx & 63;
        *(bf16x8*)&wl[o * 72 + c] = *(const bf16x8*)&W1b[g * 6144 + idx];
    }
    if (threadIdx.x < COUT_G * 2) st[threadIdx.x] = 0.f;
    __syncthreads();

    const int wid = threadIdx.x >> 6, lane = threadIdx.x & 63;
    const int lg = lane >> 4, lr = lane & 15;
    const int jw = blockIdx.x * 4 + wid;          // wave's j row (0..255)
    const float* xb = x + ((size_t)b * CIN + g * CIN_G) * NPOS;

    f32x4 acc1[6][4];
#pragma unroll
    for (int mt = 0; mt < 6; ++mt)
#pragma unroll
        for (int nt = 0; nt < 4; ++nt) acc1[mt][nt] = (f32x4){0.f,0.f,0.f,0.f};

#pragma unroll
    for (int ks = 0; ks < 2; ++ks) {
        const int c0 = ks * 32 + lg * 8;
        bf16x8 af[6];
#pragma unroll
        for (int mt = 0; mt < 6; ++mt)
            af[mt] = *(const bf16x8*)&wl[(mt * 16 + lr) * 72 + c0];
#pragma unroll
        for (int nt = 0; nt < 4; ++nt) {
            const int kcol = nt * 16 + lr;
            bf16x8 bfv;
            if (kcol < KDIM) {
                const float* xp = xb + jw * KDIM + kcol;
#pragma unroll
                for (int i = 0; i < 8; ++i) bfv[i] = (__bf16)xp[(size_t)(c0 + i) * NPOS];
            } else {
#pragma unroll
                for (int i = 0; i < 8; ++i) bfv[i] = (__bf16)0.f;
            }
#pragma unroll
            for (int mt = 0; mt < 6; ++mt)
                acc1[mt][nt] = __builtin_amdgcn_mfma_f32_16x16x32_bf16(af[mt], bfv, acc1[mt][nt], 0, 0, 0);
        }
    }

    // stats: channel o = mt*16+lg*4+r, summed over nt and lr (pad cols are exact 0)
#pragma unroll
    for (int mt = 0; mt < 6; ++mt) {
#pragma unroll
        for (int r = 0; r < 4; ++r) {
            float s = 0.f, q = 0.f;
#pragma unroll
            for (int nt = 0; nt < 4; ++nt) {
                const float v = acc1[mt][nt][r];
                s += v; q += v * v;
            }
#pragma unroll
            for (int m = 1; m <= 8; m <<= 1) {
                s += __shfl_xor(s, m);
                q += __shfl_xor(q, m);
            }
            if (lr == 0) {
                atomicAdd(&st[(mt * 16 + lg * 4 + r) * 2], s);
                atomicAdd(&st[(mt * 16 + lg * 4 + r) * 2 + 1], q);
            }
        }
    }
    __syncthreads();
    if (threadIdx.x < COUT_G) {
        atomicAdd(&sum1[g * COUT_G + threadIdx.x], st[threadIdx.x * 2]);
        atomicAdd(&sq1[g * COUT_G + threadIdx.x], st[threadIdx.x * 2 + 1]);
    }
}

// ---------------- BN coefs (shared by BN1 and BN2)
__global__ void k_fin(const float* __restrict__ sum, const float* __restrict__ sq,
                      const float* __restrict__ gamma, const float* __restrict__ beta,
                      float* __restrict__ a, float* __restrict__ bb)
{
    const int ch = blockIdx.x * blockDim.x + threadIdx.x;
    if (ch < COUT) {
        const float invN = 1.f / (float)NSTAT;
        const float mean = sum[ch] * invN;
        const float var  = sq[ch] * invN - mean * mean;
        const float rstd = rsqrtf(var + BN_EPS);
        const float av = gamma[ch] * rstd;
        a[ch]  = av;
        bb[ch] = beta[ch] - mean * av;
    }
}

// ---------------- fused: recompute h=W1@x, BN1+ELU, conv2 -> h2 bf16 (in d_out); BN2 stats
// (exact R11 configuration -- best measured)
__global__ __launch_bounds__(256, 2) void k_fused(
    const float* __restrict__ x, const __bf16* __restrict__ W1b, const __bf16* __restrict__ W2b,
    const float* __restrict__ a1, const float* __restrict__ b1,
    __bf16* __restrict__ h2b, float* __restrict__ sum2, float* __restrict__ sq2)
{
    __shared__ __bf16 wl[COUT_G * 72];            // 13824 B
    __shared__ __bf16 ht[4 * 6144];               // 49152 B: per-wave k-packed h tiles
    __shared__ float a1l[96], b1l[96], st[192];
    const int b = blockIdx.z, g = blockIdx.y;
    for (int i = threadIdx.x; i < 768; i += 256) {
        const int idx = i * 8, o = idx >> 6, c = idx & 63;
        *(bf16x8*)&wl[o * 72 + c] = *(const bf16x8*)&W1b[g * 6144 + idx];
    }
    if (threadIdx.x < 96) {
        a1l[threadIdx.x] = a1[g * 96 + threadIdx.x];
        b1l[threadIdx.x] = b1[g * 96 + threadIdx.x];
    }
    if (threadIdx.x < 192) st[threadIdx.x] = 0.f;
    __syncthreads();

    const int wid = threadIdx.x >> 6, lane = threadIdx.x & 63;
    const int lg = lane >> 4, lr = lane & 15;
    const int jw = blockIdx.x * 4 + wid;          // wave's j row (0..255)
    const float* xb = x + ((size_t)b * CIN + g * CIN_G) * NPOS;
    char* htw = (char*)(ht + wid * 6144);

    // ---- phase 1: C1[o][pos] = W1 @ x ; BN1+ELU ; swizzled k-packed LDS write
    {
        f32x4 acc1[6][4];
#pragma unroll
        for (int mt = 0; mt < 6; ++mt)
#pragma unroll
            for (int nt = 0; nt < 4; ++nt) acc1[mt][nt] = (f32x4){0.f,0.f,0.f,0.f};

#pragma unroll
        for (int ks = 0; ks < 2; ++ks) {
            const int c0 = ks * 32 + lg * 8;
            bf16x8 af[6];
#pragma unroll
            for (int mt = 0; mt < 6; ++mt)
                af[mt] = *(const bf16x8*)&wl[(mt * 16 + lr) * 72 + c0];
#pragma unroll
            for (int nt = 0; nt < 4; ++nt) {
                const int kcol = nt * 16 + lr;
                bf16x8 bfv;
                if (kcol < KDIM) {
                    const float* xp = xb + jw * KDIM + kcol;
#pragma unroll
                    for (int i = 0; i < 8; ++i) bfv[i] = (__bf16)xp[(size_t)(c0 + i) * NPOS];
                } else {
#pragma unroll
                    for (int i = 0; i < 8; ++i) bfv[i] = (__bf16)0.f;
                }
#pragma unroll
                for (int mt = 0; mt < 6; ++mt)
                    acc1[mt][nt] = __builtin_amdgcn_mfma_f32_16x16x32_bf16(af[mt], bfv, acc1[mt][nt], 0, 0, 0);
            }
        }
#pragma unroll
        for (int mt = 0; mt < 6; ++mt) {
            const int o0 = mt * 16 + lg * 4;
            const int c8 = o0 >> 3;
            const int half = (o0 & 7) >> 2;
#pragma unroll
            for (int nt = 0; nt < 4; ++nt) {
                const int pl = nt * 16 + lr;
                bf16x4 pv;
#pragma unroll
                for (int r = 0; r < 4; ++r) {
                    const int o = o0 + r;
                    float t = a1l[o] * acc1[mt][nt][r] + b1l[o];
                    t = t > 0.f ? t : (__expf(t) - 1.f);
                    pv[r] = (__bf16)t;
                }
                *(bf16x4*)(htw + c8 * 1024 + (pl ^ ((c8 & 3) << 1)) * 16 + half * 8) = pv;
            }
        }
    }

    // ---- phase 2: acc2[pos][ch] = eh @ W2^T
    f32x4 acc2[4][6];
#pragma unroll
    for (int mt = 0; mt < 4; ++mt)
#pragma unroll
        for (int nt = 0; nt < 6; ++nt) acc2[mt][nt] = (f32x4){0.f,0.f,0.f,0.f};

#pragma unroll
    for (int ks = 0; ks < 3; ++ks) {
        const int c0 = ks * 32 + lg * 8;
        const int c8r = ks * 4 + lg;
        bf16x8 a2[4];
#pragma unroll
        for (int mt = 0; mt < 4; ++mt) {
            a2[mt] = *(const bf16x8*)(htw + c8r * 1024 + ((mt * 16 + lr) ^ ((c8r & 3) << 1)) * 16);
            if (mt == 3 && lr >= 14) {            // pad pos 62,63 -> zero rows
#pragma unroll
                for (int i = 0; i < 8; ++i) a2[mt][i] = (__bf16)0.f;
            }
        }
        bf16x8 bw[6];
#pragma unroll
        for (int nt = 0; nt < 6; ++nt)
            bw[nt] = *(const bf16x8*)&W2b[((size_t)g * 96 + nt * 16 + lr) * 96 + c0];
#pragma unroll
        for (int mt = 0; mt < 4; ++mt)
#pragma unroll
            for (int nt = 0; nt < 6; ++nt)
                acc2[mt][nt] = __builtin_amdgcn_mfma_f32_16x16x32_bf16(a2[mt], bw[nt], acc2[mt][nt], 0, 0, 0);
    }

    // store h2 bf16 (sparse in d_out) + BN2 stats
#pragma unroll
    for (int nt = 0; nt < 6; ++nt) {
        const int o2 = nt * 16 + lr;
        __bf16* sb = h2b + ((size_t)b * COUT + g * 96 + o2) * SLABBF + (size_t)jw * 64;
        float s = 0.f, q = 0.f;
#pragma unroll
        for (int mt = 0; mt < 4; ++mt) {
            bf16x4 pv;
#pragma unroll
            for (int r = 0; r < 4; ++r) {
                const float v = acc2[mt][nt][r];
                s += v; q += v * v;
                pv[r] = (__bf16)v;
            }
            *(bf16x4*)&sb[mt * 16 + lg * 4] = pv;
        }
        s += __shfl_xor(s, 16); q += __shfl_xor(q, 16);
        s += __shfl_xor(s, 32); q += __shfl_xor(q, 32);
        if (lane < 16) {
            atomicAdd(&st[o2 * 2], s);
            atomicAdd(&st[o2 * 2 + 1], q);
        }
    }
    __syncthreads();
    if (threadIdx.x < 96) {
        atomicAdd(&sum2[g * 96 + threadIdx.x], st[threadIdx.x * 2]);
        atomicAdd(&sq2[g * 96 + threadIdx.x], st[threadIdx.x * 2 + 1]);
    }
}

// ---------------- adjacency (MFMA, A=L^T, B=h2^T -> C[p][j]); in-place on d_out
// CHANGE vs R11: y stores are NON-TEMPORAL (y never re-read; keeps h2 slabs hot in L2/L3)
__global__ __launch_bounds__(256) void k_adj(
    float* __restrict__ y, const float* __restrict__ L,
    const float* __restrict__ a2, const float* __restrict__ b2,
    const float* __restrict__ lcs)
{
    __shared__ __bf16 Lt[64 * 72];     // Lt[p][k], zero-padded
    __shared__ float lcl[64];
    const int ch = blockIdx.x, b = blockIdx.y;
    const int g = ch / COUT_G;
    const int s = b * COUT + ch;
    const float* Lg = L + g * KDIM * KDIM;
    const __bf16* h2b = (const __bf16*)y;

    for (int i = threadIdx.x; i < 4096; i += 256) {
        const int p = i >> 6, k = i & 63;
        Lt[p * 72 + k] = (__bf16)((p < KDIM && k < KDIM) ? Lg[k * KDIM + p] : 0.f);
    }
    if (threadIdx.x < 64)
        lcl[threadIdx.x] = (threadIdx.x < KDIM) ? lcs[g * KDIM + threadIdx.x] : 0.f;

    const int wid = threadIdx.x >> 6, lane = threadIdx.x & 63;
    const int lg = lane >> 4, lr = lane & 15;
    const int j0 = wid * 64;

    // stage ALL h2 B-frags before the barrier (barrier drains vmcnt -> safe in-place)
    bf16x8 bt[4][2];
#pragma unroll
    for (int nt = 0; nt < 4; ++nt)
#pragma unroll
        for (int ks = 0; ks < 2; ++ks)
            bt[nt][ks] = *(const bf16x8*)&h2b[(size_t)s * SLABBF + (j0 + nt * 16 + lr) * 64 + ks * 32 + lg * 8];
    __syncthreads();

    bf16x8 lt[4][2];
#pragma unroll
    for (int mt = 0; mt < 4; ++mt)
#pragma unroll
        for (int ks = 0; ks < 2; ++ks)
            lt[mt][ks] = *(const bf16x8*)&Lt[(mt * 16 + lr) * 72 + ks * 32 + lg * 8];

    f32x4 acc[4][4];
#pragma unroll
    for (int mt = 0; mt < 4; ++mt)
#pragma unroll
        for (int nt = 0; nt < 4; ++nt) acc[mt][nt] = (f32x4){0.f,0.f,0.f,0.f};

#pragma unroll
    for (int ks = 0; ks < 2; ++ks)
#pragma unroll
        for (int nt = 0; nt < 4; ++nt)
#pragma unroll
            for (int mt = 0; mt < 4; ++mt)
                acc[mt][nt] = __builtin_amdgcn_mfma_f32_16x16x32_bf16(lt[mt][ks], bt[nt][ks], acc[mt][nt], 0, 0, 0);

    const float av = a2[ch], bv = b2[ch];
#pragma unroll
    for (int nt = 0; nt < 4; ++nt) {
        const int j = j0 + nt * 16 + lr;
        float* yr = y + (size_t)s * NPOS + j * KDIM;
#pragma unroll
        for (int mt = 0; mt < 4; ++mt) {
            const int p0 = mt * 16 + lg * 4;
            f32x2 v0 = { av * acc[mt][nt][0] + bv * lcl[p0],
                         av * acc[mt][nt][1] + bv * lcl[p0 + 1] };
            __builtin_nontemporal_store(v0, (f32x2*)&yr[p0]);
            if (p0 < 60) {
                f32x2 v1 = { av * acc[mt][nt][2] + bv * lcl[p0 + 2],
                             av * acc[mt][nt][3] + bv * lcl[p0 + 3] };
                __builtin_nontemporal_store(v1, (f32x2*)&yr[p0 + 2]);
            }
        }
    }
}

extern "C" void kernel_launch(void* const* d_in, const int* in_sizes, int n_in,
                              void* d_out, int out_size, void* d_ws, size_t ws_size,
                              hipStream_t stream)
{
    const float* x      = (const float*)d_in[0];
    const float* L      = (const float*)d_in[1];
    const float* W1     = (const float*)d_in[2];
    const float* W2     = (const float*)d_in[3];
    const float* gamma1 = (const float*)d_in[4];
    const float* beta1  = (const float*)d_in[5];
    const float* gamma2 = (const float*)d_in[6];
    const float* beta2  = (const float*)d_in[7];
    float* y = (float*)d_out;

    float* ws   = (float*)d_ws;
    float* sum1 = ws;            float* sq1 = ws + 480;
    float* sum2 = ws + 960;      float* sq2 = ws + 1440;
    float* a1   = ws + 1920;     float* b1  = ws + 2400;
    float* a2   = ws + 2880;     float* b2  = ws + 3360;
    float* lcs  = ws + 3840;     // 320 (310 used)
    __bf16* W1b = (__bf16*)(ws + 4160);   // 30720 bf16
    __bf16* W2b = (__bf16*)(ws + 19520);  // 46080 bf16

    // zero sum1+sq1+sum2+sq2 (contiguous 1920 floats)
    hipMemsetAsync(ws, 0, 1920 * sizeof(float), stream);

    k_prep <<<305, 256, 0, stream>>>(W1, W2, L, W1b, W2b, lcs);
    k_stat1<<<dim3(64, G, B), 256, 0, stream>>>(x, W1b, sum1, sq1);
    k_fin  <<<2, 256, 0, stream>>>(sum1, sq1, gamma1, beta1, a1, b1);
    k_fused<<<dim3(64, G, B), 256, 0, stream>>>(x, W1b, W2b, a1, b1, (__bf16*)d_out, sum2, sq2);
    k_fin  <<<2, 256, 0, stream>>>(sum2, sq2, gamma2, beta2, a2, b2);
    k_adj  <<<dim3(COUT, B), 256, 0, stream>>>(y, L, a2, b2, lcs);
}

// Round 15
// 253.866 us; speedup vs baseline: 1.1973x; 1.1973x over previous
//
#include <hip/hip_runtime.h>
#include <hip/hip_bf16.h>

#define G 5
#define B 8
#define CIN 320
#define CIN_G 64
#define COUT 480
#define COUT_G 96
#define NPOS 15872
#define NSTAT (B*NPOS)
#define BN_EPS 1e-5f
#define KDIM 62
#define SLABBF 31744        // bf16 slots per (b,ch) slab region of d_out

typedef float  f32x4 __attribute__((ext_vector_type(4)));
typedef float  f32x2 __attribute__((ext_vector_type(2)));
typedef __bf16 bf16x8 __attribute__((ext_vector_type(8)));
typedef __bf16 bf16x4 __attribute__((ext_vector_type(4)));

// ---------------- prep: W1,W2 -> bf16; L column sums
__global__ __launch_bounds__(256) void k_prep(
    const float* __restrict__ W1, const float* __restrict__ W2, const float* __restrict__ L,
    __bf16* __restrict__ W1b, __bf16* __restrict__ W2b, float* __restrict__ lcs)
{
    const int bx = blockIdx.x;
    if (bx < 300) {
        const int i = bx * 256 + threadIdx.x;
        if (i < 30720) W1b[i] = (__bf16)W1[i];
        else W2b[i - 30720] = (__bf16)W2[i - 30720];
    } else {
        const int g = bx - 300, p = threadIdx.x;
        if (p < KDIM) {
            float s = 0.f;
            for (int k = 0; k < KDIM; ++k) s += L[(g * KDIM + k) * KDIM + p];
            lcs[g * KDIM + p] = s;
        }
    }
}

// ---------------- BN1 stats pass: conv1 to REGISTERS only (no h store), reduce stats.
__global__ __launch_bounds__(256) void k_stat1(
    const float* __restrict__ x, const __bf16* __restrict__ W1b,
    float* __restrict__ sum1, float* __restrict__ sq1)
{
    __shared__ __bf16 wl[COUT_G * 72];            // 13824 B
    __shared__ float st[COUT_G * 2];
    const int b = blockIdx.z, g = blockIdx.y;
    for (int i = threadIdx.x; i < 768; i += 256) {
        const int idx = i * 8, o = idx >> 6, c = idx & 63;
        *(bf16x8*)&wl[o * 72 + c] = *(const bf16x8*)&W1b[g * 6144 + idx];
    }
    if (threadIdx.x < COUT_G * 2) st[threadIdx.x] = 0.f;
    __syncthreads();

    const int wid = threadIdx.x >> 6, lane = threadIdx.x & 63;
    const int lg = lane >> 4, lr = lane & 15;
    const int jw = blockIdx.x * 4 + wid;          // wave's j row (0..255)
    const float* xb = x + ((size_t)b * CIN + g * CIN_G) * NPOS;

    f32x4 acc1[6][4];
#pragma unroll
    for (int mt = 0; mt < 6; ++mt)
#pragma unroll
        for (int nt = 0; nt < 4; ++nt) acc1[mt][nt] = (f32x4){0.f,0.f,0.f,0.f};

#pragma unroll
    for (int ks = 0; ks < 2; ++ks) {
        const int c0 = ks * 32 + lg * 8;
        bf16x8 af[6];
#pragma unroll
        for (int mt = 0; mt < 6; ++mt)
            af[mt] = *(const bf16x8*)&wl[(mt * 16 + lr) * 72 + c0];
#pragma unroll
        for (int nt = 0; nt < 4; ++nt) {
            const int kcol = nt * 16 + lr;
            bf16x8 bfv;
            if (kcol < KDIM) {
                const float* xp = xb + jw * KDIM + kcol;
#pragma unroll
                for (int i = 0; i < 8; ++i) bfv[i] = (__bf16)xp[(size_t)(c0 + i) * NPOS];
            } else {
#pragma unroll
                for (int i = 0; i < 8; ++i) bfv[i] = (__bf16)0.f;
            }
#pragma unroll
            for (int mt = 0; mt < 6; ++mt)
                acc1[mt][nt] = __builtin_amdgcn_mfma_f32_16x16x32_bf16(af[mt], bfv, acc1[mt][nt], 0, 0, 0);
        }
    }

    // stats: channel o = mt*16+lg*4+r, summed over nt and lr (pad cols are exact 0)
#pragma unroll
    for (int mt = 0; mt < 6; ++mt) {
#pragma unroll
        for (int r = 0; r < 4; ++r) {
            float s = 0.f, q = 0.f;
#pragma unroll
            for (int nt = 0; nt < 4; ++nt) {
                const float v = acc1[mt][nt][r];
                s += v; q += v * v;
            }
#pragma unroll
            for (int m = 1; m <= 8; m <<= 1) {
                s += __shfl_xor(s, m);
                q += __shfl_xor(q, m);
            }
            if (lr == 0) {
                atomicAdd(&st[(mt * 16 + lg * 4 + r) * 2], s);
                atomicAdd(&st[(mt * 16 + lg * 4 + r) * 2 + 1], q);
            }
        }
    }
    __syncthreads();
    if (threadIdx.x < COUT_G) {
        atomicAdd(&sum1[g * COUT_G + threadIdx.x], st[threadIdx.x * 2]);
        atomicAdd(&sq1[g * COUT_G + threadIdx.x], st[threadIdx.x * 2 + 1]);
    }
}

// ---------------- BN coefs (shared by BN1 and BN2)
__global__ void k_fin(const float* __restrict__ sum, const float* __restrict__ sq,
                      const float* __restrict__ gamma, const float* __restrict__ beta,
                      float* __restrict__ a, float* __restrict__ bb)
{
    const int ch = blockIdx.x * blockDim.x + threadIdx.x;
    if (ch < COUT) {
        const float invN = 1.f / (float)NSTAT;
        const float mean = sum[ch] * invN;
        const float var  = sq[ch] * invN - mean * mean;
        const float rstd = rsqrtf(var + BN_EPS);
        const float av = gamma[ch] * rstd;
        a[ch]  = av;
        bb[ch] = beta[ch] - mean * av;
    }
}

// ---------------- fused: recompute h=W1@x, BN1+ELU, conv2 -> h2 bf16 (in d_out); BN2 stats
// (exact R11 configuration -- best measured)
__global__ __launch_bounds__(256, 2) void k_fused(
    const float* __restrict__ x, const __bf16* __restrict__ W1b, const __bf16* __restrict__ W2b,
    const float* __restrict__ a1, const float* __restrict__ b1,
    __bf16* __restrict__ h2b, float* __restrict__ sum2, float* __restrict__ sq2)
{
    __shared__ __bf16 wl[COUT_G * 72];            // 13824 B
    __shared__ __bf16 ht[4 * 6144];               // 49152 B: per-wave k-packed h tiles
    __shared__ float a1l[96], b1l[96], st[192];
    const int b = blockIdx.z, g = blockIdx.y;
    for (int i = threadIdx.x; i < 768; i += 256) {
        const int idx = i * 8, o = idx >> 6, c = idx & 63;
        *(bf16x8*)&wl[o * 72 + c] = *(const bf16x8*)&W1b[g * 6144 + idx];
    }
    if (threadIdx.x < 96) {
        a1l[threadIdx.x] = a1[g * 96 + threadIdx.x];
        b1l[threadIdx.x] = b1[g * 96 + threadIdx.x];
    }
    if (threadIdx.x < 192) st[threadIdx.x] = 0.f;
    __syncthreads();

    const int wid = threadIdx.x >> 6, lane = threadIdx.x & 63;
    const int lg = lane >> 4, lr = lane & 15;
    const int jw = blockIdx.x * 4 + wid;          // wave's j row (0..255)
    const float* xb = x + ((size_t)b * CIN + g * CIN_G) * NPOS;
    char* htw = (char*)(ht + wid * 6144);

    // ---- phase 1: C1[o][pos] = W1 @ x ; BN1+ELU ; swizzled k-packed LDS write
    {
        f32x4 acc1[6][4];
#pragma unroll
        for (int mt = 0; mt < 6; ++mt)
#pragma unroll
            for (int nt = 0; nt < 4; ++nt) acc1[mt][nt] = (f32x4){0.f,0.f,0.f,0.f};

#pragma unroll
        for (int ks = 0; ks < 2; ++ks) {
            const int c0 = ks * 32 + lg * 8;
            bf16x8 af[6];
#pragma unroll
            for (int mt = 0; mt < 6; ++mt)
                af[mt] = *(const bf16x8*)&wl[(mt * 16 + lr) * 72 + c0];
#pragma unroll
            for (int nt = 0; nt < 4; ++nt) {
                const int kcol = nt * 16 + lr;
                bf16x8 bfv;
                if (kcol < KDIM) {
                    const float* xp = xb + jw * KDIM + kcol;
#pragma unroll
                    for (int i = 0; i < 8; ++i) bfv[i] = (__bf16)xp[(size_t)(c0 + i) * NPOS];
                } else {
#pragma unroll
                    for (int i = 0; i < 8; ++i) bfv[i] = (__bf16)0.f;
                }
#pragma unroll
                for (int mt = 0; mt < 6; ++mt)
                    acc1[mt][nt] = __builtin_amdgcn_mfma_f32_16x16x32_bf16(af[mt], bfv, acc1[mt][nt], 0, 0, 0);
            }
        }
#pragma unroll
        for (int mt = 0; mt < 6; ++mt) {
            const int o0 = mt * 16 + lg * 4;
            const int c8 = o0 >> 3;
            const int half = (o0 & 7) >> 2;
#pragma unroll
            for (int nt = 0; nt < 4; ++nt) {
                const int pl = nt * 16 + lr;
                bf16x4 pv;
#pragma unroll
                for (int r = 0; r < 4; ++r) {
                    const int o = o0 + r;
                    float t = a1l[o] * acc1[mt][nt][r] + b1l[o];
                    t = t > 0.f ? t : (__expf(t) - 1.f);
                    pv[r] = (__bf16)t;
                }
                *(bf16x4*)(htw + c8 * 1024 + (pl ^ ((c8 & 3) << 1)) * 16 + half * 8) = pv;
            }
        }
    }

    // ---- phase 2: acc2[pos][ch] = eh @ W2^T
    f32x4 acc2[4][6];
#pragma unroll
    for (int mt = 0; mt < 4; ++mt)
#pragma unroll
        for (int nt = 0; nt < 6; ++nt) acc2[mt][nt] = (f32x4){0.f,0.f,0.f,0.f};

#pragma unroll
    for (int ks = 0; ks < 3; ++ks) {
        const int c0 = ks * 32 + lg * 8;
        const int c8r = ks * 4 + lg;
        bf16x8 a2[4];
#pragma unroll
        for (int mt = 0; mt < 4; ++mt) {
            a2[mt] = *(const bf16x8*)(htw + c8r * 1024 + ((mt * 16 + lr) ^ ((c8r & 3) << 1)) * 16);
            if (mt == 3 && lr >= 14) {            // pad pos 62,63 -> zero rows
#pragma unroll
                for (int i = 0; i < 8; ++i) a2[mt][i] = (__bf16)0.f;
            }
        }
        bf16x8 bw[6];
#pragma unroll
        for (int nt = 0; nt < 6; ++nt)
            bw[nt] = *(const bf16x8*)&W2b[((size_t)g * 96 + nt * 16 + lr) * 96 + c0];
#pragma unroll
        for (int mt = 0; mt < 4; ++mt)
#pragma unroll
            for (int nt = 0; nt < 6; ++nt)
                acc2[mt][nt] = __builtin_amdgcn_mfma_f32_16x16x32_bf16(a2[mt], bw[nt], acc2[mt][nt], 0, 0, 0);
    }

    // store h2 bf16 (sparse in d_out) + BN2 stats
#pragma unroll
    for (int nt = 0; nt < 6; ++nt) {
        const int o2 = nt * 16 + lr;
        __bf16* sb = h2b + ((size_t)b * COUT + g * 96 + o2) * SLABBF + (size_t)jw * 64;
        float s = 0.f, q = 0.f;
#pragma unroll
        for (int mt = 0; mt < 4; ++mt) {
            bf16x4 pv;
#pragma unroll
            for (int r = 0; r < 4; ++r) {
                const float v = acc2[mt][nt][r];
                s += v; q += v * v;
                pv[r] = (__bf16)v;
            }
            *(bf16x4*)&sb[mt * 16 + lg * 4] = pv;
        }
        s += __shfl_xor(s, 16); q += __shfl_xor(q, 16);
        s += __shfl_xor(s, 32); q += __shfl_xor(q, 32);
        if (lane < 16) {
            atomicAdd(&st[o2 * 2], s);
            atomicAdd(&st[o2 * 2 + 1], q);
        }
    }
    __syncthreads();
    if (threadIdx.x < 96) {
        atomicAdd(&sum2[g * 96 + threadIdx.x], st[threadIdx.x * 2]);
        atomicAdd(&sq2[g * 96 + threadIdx.x], st[threadIdx.x * 2 + 1]);
    }
}

// ---------------- adjacency (MFMA, A=L^T, B=h2^T -> C[p][j]); in-place on d_out
// CHANGE vs R11: epilogue goes through a wave-private LDS y-tile, then streams out
// as 31 fully-contiguous 512B store instructions per wave (was 32 stores of
// 16 x 8B scattered at 248B stride -- 16 partial cache lines per instruction).
__global__ __launch_bounds__(256) void k_adj(
    float* __restrict__ y, const float* __restrict__ L,
    const float* __restrict__ a2, const float* __restrict__ b2,
    const float* __restrict__ lcs)
{
    __shared__ __bf16 Lt[64 * 72];     // 9216 B: Lt[p][k], zero-padded
    __shared__ float lcl[64];
    __shared__ float yt[4][64 * KDIM]; // 63488 B: per-wave 64x62 f32 y tile
    const int ch = blockIdx.x, b = blockIdx.y;
    const int g = ch / COUT_G;
    const int s = b * COUT + ch;
    const float* Lg = L + g * KDIM * KDIM;
    const __bf16* h2b = (const __bf16*)y;

    for (int i = threadIdx.x; i < 4096; i += 256) {
        const int p = i >> 6, k = i & 63;
        Lt[p * 72 + k] = (__bf16)((p < KDIM && k < KDIM) ? Lg[k * KDIM + p] : 0.f);
    }
    if (threadIdx.x < 64)
        lcl[threadIdx.x] = (threadIdx.x < KDIM) ? lcs[g * KDIM + threadIdx.x] : 0.f;

    const int wid = threadIdx.x >> 6, lane = threadIdx.x & 63;
    const int lg = lane >> 4, lr = lane & 15;
    const int j0 = wid * 64;

    // stage ALL h2 B-frags before the barrier (barrier drains vmcnt -> safe in-place)
    bf16x8 bt[4][2];
#pragma unroll
    for (int nt = 0; nt < 4; ++nt)
#pragma unroll
        for (int ks = 0; ks < 2; ++ks)
            bt[nt][ks] = *(const bf16x8*)&h2b[(size_t)s * SLABBF + (j0 + nt * 16 + lr) * 64 + ks * 32 + lg * 8];
    __syncthreads();

    bf16x8 lt[4][2];
#pragma unroll
    for (int mt = 0; mt < 4; ++mt)
#pragma unroll
        for (int ks = 0; ks < 2; ++ks)
            lt[mt][ks] = *(const bf16x8*)&Lt[(mt * 16 + lr) * 72 + ks * 32 + lg * 8];

    f32x4 acc[4][4];
#pragma unroll
    for (int mt = 0; mt < 4; ++mt)
#pragma unroll
        for (int nt = 0; nt < 4; ++nt) acc[mt][nt] = (f32x4){0.f,0.f,0.f,0.f};

#pragma unroll
    for (int ks = 0; ks < 2; ++ks)
#pragma unroll
        for (int nt = 0; nt < 4; ++nt)
#pragma unroll
            for (int mt = 0; mt < 4; ++mt)
                acc[mt][nt] = __builtin_amdgcn_mfma_f32_16x16x32_bf16(lt[mt][ks], bt[nt][ks], acc[mt][nt], 0, 0, 0);

    const float av = a2[ch], bv = b2[ch];
    float* ytw = yt[wid];
    // write wave's 64x62 tile to LDS (f32x2 pieces: 8B-aligned; row stride 62
    // dwords -> 30-bank stagger across the 16 j-lanes, conflict-free)
#pragma unroll
    for (int nt = 0; nt < 4; ++nt) {
        const int jl = nt * 16 + lr;              // local j 0..63
#pragma unroll
        for (int mt = 0; mt < 4; ++mt) {
            const int p0 = mt * 16 + lg * 4;
            f32x2 v0 = { av * acc[mt][nt][0] + bv * lcl[p0],
                         av * acc[mt][nt][1] + bv * lcl[p0 + 1] };
            *(f32x2*)&ytw[jl * KDIM + p0] = v0;
            if (p0 < 60) {
                f32x2 v1 = { av * acc[mt][nt][2] + bv * lcl[p0 + 2],
                             av * acc[mt][nt][3] + bv * lcl[p0 + 3] };
                *(f32x2*)&ytw[jl * KDIM + p0 + 2] = v1;
            }
        }
    }
    // wave-private region: no barrier needed; compiler orders via lgkmcnt.
    // flat coalesced flush: 64*62 floats = 1984 f32x2 chunks = 31 per lane.
    float* yg = y + (size_t)s * NPOS + j0 * KDIM;
#pragma unroll
    for (int it = 0; it < 31; ++it) {
        const int idx = it * 64 + lane;
        *(f32x2*)&yg[idx * 2] = *(const f32x2*)&ytw[idx * 2];
    }
}

extern "C" void kernel_launch(void* const* d_in, const int* in_sizes, int n_in,
                              void* d_out, int out_size, void* d_ws, size_t ws_size,
                              hipStream_t stream)
{
    const float* x      = (const float*)d_in[0];
    const float* L      = (const float*)d_in[1];
    const float* W1     = (const float*)d_in[2];
    const float* W2     = (const float*)d_in[3];
    const float* gamma1 = (const float*)d_in[4];
    const float* beta1  = (const float*)d_in[5];
    const float* gamma2 = (const float*)d_in[6];
    const float* beta2  = (const float*)d_in[7];
    float* y = (float*)d_out;

    float* ws   = (float*)d_ws;
    float* sum1 = ws;            float* sq1 = ws + 480;
    float* sum2 = ws + 960;      float* sq2 = ws + 1440;
    float* a1   = ws + 1920;     float* b1  = ws + 2400;
    float* a2   = ws + 2880;     float* b2  = ws + 3360;
    float* lcs  = ws + 3840;     // 320 (310 used)
    __bf16* W1b = (__bf16*)(ws + 4160);   // 30720 bf16
    __bf16* W2b = (__bf16*)(ws + 19520);  // 46080 bf16

    // zero sum1+sq1+sum2+sq2 (contiguous 1920 floats)
    hipMemsetAsync(ws, 0, 1920 * sizeof(float), stream);

    k_prep <<<305, 256, 0, stream>>>(W1, W2, L, W1b, W2b, lcs);
    k_stat1<<<dim3(64, G, B), 256, 0, stream>>>(x, W1b, sum1, sq1);
    k_fin  <<<2, 256, 0, stream>>>(sum1, sq1, gamma1, beta1, a1, b1);
    k_fused<<<dim3(64, G, B), 256, 0, stream>>>(x, W1b, W2b, a1, b1, (__bf16*)d_out, sum2, sq2);
    k_fin  <<<2, 256, 0, stream>>>(sum2, sq2, gamma2, beta2, a2, b2);
    k_adj  <<<dim3(COUT, B), 256, 0, stream>>>(y, L, a2, b2, lcs);
}

// Round 16
// 253.028 us; speedup vs baseline: 1.2013x; 1.0033x over previous
//
#include <hip/hip_runtime.h>
#include <hip/hip_bf16.h>

#define G 5
#define B 8
#define CIN 320
#define CIN_G 64
#define COUT 480
#define COUT_G 96
#define NPOS 15872
#define NSTAT (B*NPOS)
#define BN_EPS 1e-5f
#define KDIM 62
#define SLABBF 31744        // bf16 slots per (b,ch) slab region of d_out

typedef float  f32x4 __attribute__((ext_vector_type(4)));
typedef float  f32x2 __attribute__((ext_vector_type(2)));
typedef __bf16 bf16x8 __attribute__((ext_vector_type(8)));
typedef __bf16 bf16x4 __attribute__((ext_vector_type(4)));

// ---------------- prep: W1,W2 -> bf16; L column sums (stride-64 padded for f32x4 reads)
__global__ __launch_bounds__(256) void k_prep(
    const float* __restrict__ W1, const float* __restrict__ W2, const float* __restrict__ L,
    __bf16* __restrict__ W1b, __bf16* __restrict__ W2b, float* __restrict__ lcs)
{
    const int bx = blockIdx.x;
    if (bx < 300) {
        const int i = bx * 256 + threadIdx.x;
        if (i < 30720) W1b[i] = (__bf16)W1[i];
        else W2b[i - 30720] = (__bf16)W2[i - 30720];
    } else {
        const int g = bx - 300, p = threadIdx.x;
        if (p < 64) {
            float s = 0.f;
            if (p < KDIM)
                for (int k = 0; k < KDIM; ++k) s += L[(g * KDIM + k) * KDIM + p];
            lcs[g * 64 + p] = s;
        }
    }
}

// ---------------- BN1 stats pass: conv1 to REGISTERS only (no h store), reduce stats.
__global__ __launch_bounds__(256) void k_stat1(
    const float* __restrict__ x, const __bf16* __restrict__ W1b,
    float* __restrict__ sum1, float* __restrict__ sq1)
{
    __shared__ __bf16 wl[COUT_G * 72];            // 13824 B
    __shared__ float st[COUT_G * 2];
    const int b = blockIdx.z, g = blockIdx.y;
    for (int i = threadIdx.x; i < 768; i += 256) {
        const int idx = i * 8, o = idx >> 6, c = idx & 63;
        *(bf16x8*)&wl[o * 72 + c] = *(const bf16x8*)&W1b[g * 6144 + idx];
    }
    if (threadIdx.x < COUT_G * 2) st[threadIdx.x] = 0.f;
    __syncthreads();

    const int wid = threadIdx.x >> 6, lane = threadIdx.x & 63;
    const int lg = lane >> 4, lr = lane & 15;
    const int jw = blockIdx.x * 4 + wid;          // wave's j row (0..255)
    const float* xb = x + ((size_t)b * CIN + g * CIN_G) * NPOS;

    f32x4 acc1[6][4];
#pragma unroll
    for (int mt = 0; mt < 6; ++mt)
#pragma unroll
        for (int nt = 0; nt < 4; ++nt) acc1[mt][nt] = (f32x4){0.f,0.f,0.f,0.f};

#pragma unroll
    for (int ks = 0; ks < 2; ++ks) {
        const int c0 = ks * 32 + lg * 8;
        bf16x8 af[6];
#pragma unroll
        for (int mt = 0; mt < 6; ++mt)
            af[mt] = *(const bf16x8*)&wl[(mt * 16 + lr) * 72 + c0];
#pragma unroll
        for (int nt = 0; nt < 4; ++nt) {
            const int kcol = nt * 16 + lr;
            bf16x8 bfv;
            if (kcol < KDIM) {
                const float* xp = xb + jw * KDIM + kcol;
#pragma unroll
                for (int i = 0; i < 8; ++i) bfv[i] = (__bf16)xp[(size_t)(c0 + i) * NPOS];
            } else {
#pragma unroll
                for (int i = 0; i < 8; ++i) bfv[i] = (__bf16)0.f;
            }
#pragma unroll
            for (int mt = 0; mt < 6; ++mt)
                acc1[mt][nt] = __builtin_amdgcn_mfma_f32_16x16x32_bf16(af[mt], bfv, acc1[mt][nt], 0, 0, 0);
        }
    }

    // stats: channel o = mt*16+lg*4+r, summed over nt and lr (pad cols are exact 0)
#pragma unroll
    for (int mt = 0; mt < 6; ++mt) {
#pragma unroll
        for (int r = 0; r < 4; ++r) {
            float s = 0.f, q = 0.f;
#pragma unroll
            for (int nt = 0; nt < 4; ++nt) {
                const float v = acc1[mt][nt][r];
                s += v; q += v * v;
            }
#pragma unroll
            for (int m = 1; m <= 8; m <<= 1) {
                s += __shfl_xor(s, m);
                q += __shfl_xor(q, m);
            }
            if (lr == 0) {
                atomicAdd(&st[(mt * 16 + lg * 4 + r) * 2], s);
                atomicAdd(&st[(mt * 16 + lg * 4 + r) * 2 + 1], q);
            }
        }
    }
    __syncthreads();
    if (threadIdx.x < COUT_G) {
        atomicAdd(&sum1[g * COUT_G + threadIdx.x], st[threadIdx.x * 2]);
        atomicAdd(&sq1[g * COUT_G + threadIdx.x], st[threadIdx.x * 2 + 1]);
    }
}

// ---------------- BN coefs (shared by BN1 and BN2)
__global__ void k_fin(const float* __restrict__ sum, const float* __restrict__ sq,
                      const float* __restrict__ gamma, const float* __restrict__ beta,
                      float* __restrict__ a, float* __restrict__ bb)
{
    const int ch = blockIdx.x * blockDim.x + threadIdx.x;
    if (ch < COUT) {
        const float invN = 1.f / (float)NSTAT;
        const float mean = sum[ch] * invN;
        const float var  = sq[ch] * invN - mean * mean;
        const float rstd = rsqrtf(var + BN_EPS);
        const float av = gamma[ch] * rstd;
        a[ch]  = av;
        bb[ch] = beta[ch] - mean * av;
    }
}

// ---------------- fused: recompute h=W1@x, BN1+ELU, conv2 -> h2 bf16 (in d_out); BN2 stats
// (exact R11 configuration -- best measured)
__global__ __launch_bounds__(256, 2) void k_fused(
    const float* __restrict__ x, const __bf16* __restrict__ W1b, const __bf16* __restrict__ W2b,
    const float* __restrict__ a1, const float* __restrict__ b1,
    __bf16* __restrict__ h2b, float* __restrict__ sum2, float* __restrict__ sq2)
{
    __shared__ __bf16 wl[COUT_G * 72];            // 13824 B
    __shared__ __bf16 ht[4 * 6144];               // 49152 B: per-wave k-packed h tiles
    __shared__ float a1l[96], b1l[96], st[192];
    const int b = blockIdx.z, g = blockIdx.y;
    for (int i = threadIdx.x; i < 768; i += 256) {
        const int idx = i * 8, o = idx >> 6, c = idx & 63;
        *(bf16x8*)&wl[o * 72 + c] = *(const bf16x8*)&W1b[g * 6144 + idx];
    }
    if (threadIdx.x < 96) {
        a1l[threadIdx.x] = a1[g * 96 + threadIdx.x];
        b1l[threadIdx.x] = b1[g * 96 + threadIdx.x];
    }
    if (threadIdx.x < 192) st[threadIdx.x] = 0.f;
    __syncthreads();

    const int wid = threadIdx.x >> 6, lane = threadIdx.x & 63;
    const int lg = lane >> 4, lr = lane & 15;
    const int jw = blockIdx.x * 4 + wid;          // wave's j row (0..255)
    const float* xb = x + ((size_t)b * CIN + g * CIN_G) * NPOS;
    char* htw = (char*)(ht + wid * 6144);

    // ---- phase 1: C1[o][pos] = W1 @ x ; BN1+ELU ; swizzled k-packed LDS write
    {
        f32x4 acc1[6][4];
#pragma unroll
        for (int mt = 0; mt < 6; ++mt)
#pragma unroll
            for (int nt = 0; nt < 4; ++nt) acc1[mt][nt] = (f32x4){0.f,0.f,0.f,0.f};

#pragma unroll
        for (int ks = 0; ks < 2; ++ks) {
            const int c0 = ks * 32 + lg * 8;
            bf16x8 af[6];
#pragma unroll
            for (int mt = 0; mt < 6; ++mt)
                af[mt] = *(const bf16x8*)&wl[(mt * 16 + lr) * 72 + c0];
#pragma unroll
            for (int nt = 0; nt < 4; ++nt) {
                const int kcol = nt * 16 + lr;
                bf16x8 bfv;
                if (kcol < KDIM) {
                    const float* xp = xb + jw * KDIM + kcol;
#pragma unroll
                    for (int i = 0; i < 8; ++i) bfv[i] = (__bf16)xp[(size_t)(c0 + i) * NPOS];
                } else {
#pragma unroll
                    for (int i = 0; i < 8; ++i) bfv[i] = (__bf16)0.f;
                }
#pragma unroll
                for (int mt = 0; mt < 6; ++mt)
                    acc1[mt][nt] = __builtin_amdgcn_mfma_f32_16x16x32_bf16(af[mt], bfv, acc1[mt][nt], 0, 0, 0);
            }
        }
#pragma unroll
        for (int mt = 0; mt < 6; ++mt) {
            const int o0 = mt * 16 + lg * 4;
            const int c8 = o0 >> 3;
            const int half = (o0 & 7) >> 2;
#pragma unroll
            for (int nt = 0; nt < 4; ++nt) {
                const int pl = nt * 16 + lr;
                bf16x4 pv;
#pragma unroll
                for (int r = 0; r < 4; ++r) {
                    const int o = o0 + r;
                    float t = a1l[o] * acc1[mt][nt][r] + b1l[o];
                    t = t > 0.f ? t : (__expf(t) - 1.f);
                    pv[r] = (__bf16)t;
                }
                *(bf16x4*)(htw + c8 * 1024 + (pl ^ ((c8 & 3) << 1)) * 16 + half * 8) = pv;
            }
        }
    }

    // ---- phase 2: acc2[pos][ch] = eh @ W2^T
    f32x4 acc2[4][6];
#pragma unroll
    for (int mt = 0; mt < 4; ++mt)
#pragma unroll
        for (int nt = 0; nt < 6; ++nt) acc2[mt][nt] = (f32x4){0.f,0.f,0.f,0.f};

#pragma unroll
    for (int ks = 0; ks < 3; ++ks) {
        const int c0 = ks * 32 + lg * 8;
        const int c8r = ks * 4 + lg;
        bf16x8 a2[4];
#pragma unroll
        for (int mt = 0; mt < 4; ++mt) {
            a2[mt] = *(const bf16x8*)(htw + c8r * 1024 + ((mt * 16 + lr) ^ ((c8r & 3) << 1)) * 16);
            if (mt == 3 && lr >= 14) {            // pad pos 62,63 -> zero rows
#pragma unroll
                for (int i = 0; i < 8; ++i) a2[mt][i] = (__bf16)0.f;
            }
        }
        bf16x8 bw[6];
#pragma unroll
        for (int nt = 0; nt < 6; ++nt)
            bw[nt] = *(const bf16x8*)&W2b[((size_t)g * 96 + nt * 16 + lr) * 96 + c0];
#pragma unroll
        for (int mt = 0; mt < 4; ++mt)
#pragma unroll
            for (int nt = 0; nt < 6; ++nt)
                acc2[mt][nt] = __builtin_amdgcn_mfma_f32_16x16x32_bf16(a2[mt], bw[nt], acc2[mt][nt], 0, 0, 0);
    }

    // store h2 bf16 (sparse in d_out) + BN2 stats
#pragma unroll
    for (int nt = 0; nt < 6; ++nt) {
        const int o2 = nt * 16 + lr;
        __bf16* sb = h2b + ((size_t)b * COUT + g * 96 + o2) * SLABBF + (size_t)jw * 64;
        float s = 0.f, q = 0.f;
#pragma unroll
        for (int mt = 0; mt < 4; ++mt) {
            bf16x4 pv;
#pragma unroll
            for (int r = 0; r < 4; ++r) {
                const float v = acc2[mt][nt][r];
                s += v; q += v * v;
                pv[r] = (__bf16)v;
            }
            *(bf16x4*)&sb[mt * 16 + lg * 4] = pv;
        }
        s += __shfl_xor(s, 16); q += __shfl_xor(q, 16);
        s += __shfl_xor(s, 32); q += __shfl_xor(q, 32);
        if (lane < 16) {
            atomicAdd(&st[o2 * 2], s);
            atomicAdd(&st[o2 * 2 + 1], q);
        }
    }
    __syncthreads();
    if (threadIdx.x < 96) {
        atomicAdd(&sum2[g * 96 + threadIdx.x], st[threadIdx.x * 2]);
        atomicAdd(&sq2[g * 96 + threadIdx.x], st[threadIdx.x * 2 + 1]);
    }
}

// ---------------- adjacency (MFMA, A=L^T, B=h2^T -> C[p][j]); in-place on d_out
// CHANGE vs R15: LDS 73KB -> 40KB (chunked y-flush, lcl->global f32x4) => 4 blocks/CU
__global__ __launch_bounds__(256) void k_adj(
    float* __restrict__ y, const float* __restrict__ L,
    const float* __restrict__ a2, const float* __restrict__ b2,
    const float* __restrict__ lcs)
{
    __shared__ __bf16 Lt[64 * 72];       // 9216 B: Lt[p][k], zero-padded
    __shared__ float yt[4][32 * KDIM];   // 31744 B: per-wave 32x62 f32 y half-tile
    const int ch = blockIdx.x, b = blockIdx.y;
    const int g = ch / COUT_G;
    const int s = b * COUT + ch;
    const float* Lg = L + g * KDIM * KDIM;
    const __bf16* h2b = (const __bf16*)y;

    for (int i = threadIdx.x; i < 4096; i += 256) {
        const int p = i >> 6, k = i & 63;
        Lt[p * 72 + k] = (__bf16)((p < KDIM && k < KDIM) ? Lg[k * KDIM + p] : 0.f);
    }

    const int wid = threadIdx.x >> 6, lane = threadIdx.x & 63;
    const int lg = lane >> 4, lr = lane & 15;
    const int j0 = wid * 64;

    // stage ALL h2 B-frags before the barrier (barrier drains vmcnt -> safe in-place)
    bf16x8 bt[4][2];
#pragma unroll
    for (int nt = 0; nt < 4; ++nt)
#pragma unroll
        for (int ks = 0; ks < 2; ++ks)
            bt[nt][ks] = *(const bf16x8*)&h2b[(size_t)s * SLABBF + (j0 + nt * 16 + lr) * 64 + ks * 32 + lg * 8];
    __syncthreads();

    bf16x8 lt[4][2];
#pragma unroll
    for (int mt = 0; mt < 4; ++mt)
#pragma unroll
        for (int ks = 0; ks < 2; ++ks)
            lt[mt][ks] = *(const bf16x8*)&Lt[(mt * 16 + lr) * 72 + ks * 32 + lg * 8];

    f32x4 acc[4][4];
#pragma unroll
    for (int mt = 0; mt < 4; ++mt)
#pragma unroll
        for (int nt = 0; nt < 4; ++nt) acc[mt][nt] = (f32x4){0.f,0.f,0.f,0.f};

#pragma unroll
    for (int ks = 0; ks < 2; ++ks)
#pragma unroll
        for (int nt = 0; nt < 4; ++nt)
#pragma unroll
            for (int mt = 0; mt < 4; ++mt)
                acc[mt][nt] = __builtin_amdgcn_mfma_f32_16x16x32_bf16(lt[mt][ks], bt[nt][ks], acc[mt][nt], 0, 0, 0);

    const float av = a2[ch], bv = b2[ch];
    f32x4 lcv[4];
#pragma unroll
    for (int mt = 0; mt < 4; ++mt)
        lcv[mt] = *(const f32x4*)&lcs[g * 64 + mt * 16 + lg * 4];   // 16B-aligned (stride-64 pad)

    float* ytw = yt[wid];
    // two halves: compute 32 rows into LDS, flush as contiguous 256B/instr dword stream.
    // wave-private region -> no barriers; per-wave LDS ordering handles the roundtrip.
#pragma unroll
    for (int half = 0; half < 2; ++half) {
#pragma unroll
        for (int nth = 0; nth < 2; ++nth) {
            const int nt = half * 2 + nth;
            const int row = nth * 16 + lr;       // 0..31 within half
#pragma unroll
            for (int mt = 0; mt < 4; ++mt) {
                const int p0 = mt * 16 + lg * 4;
                f32x2 v0 = { av * acc[mt][nt][0] + bv * lcv[mt][0],
                             av * acc[mt][nt][1] + bv * lcv[mt][1] };
                *(f32x2*)&ytw[row * KDIM + p0] = v0;
                if (p0 < 60) {
                    f32x2 v1 = { av * acc[mt][nt][2] + bv * lcv[mt][2],
                                 av * acc[mt][nt][3] + bv * lcv[mt][3] };
                    *(f32x2*)&ytw[row * KDIM + p0 + 2] = v1;
                }
            }
        }
        float* yg = y + (size_t)s * NPOS + (j0 + half * 32) * KDIM;
#pragma unroll
        for (int it = 0; it < 31; ++it) {        // 32*62 = 1984 dwords = 31/lane
            const int idx = it * 64 + lane;
            yg[idx] = ytw[idx];
        }
    }
}

extern "C" void kernel_launch(void* const* d_in, const int* in_sizes, int n_in,
                              void* d_out, int out_size, void* d_ws, size_t ws_size,
                              hipStream_t stream)
{
    const float* x      = (const float*)d_in[0];
    const float* L      = (const float*)d_in[1];
    const float* W1     = (const float*)d_in[2];
    const float* W2     = (const float*)d_in[3];
    const float* gamma1 = (const float*)d_in[4];
    const float* beta1  = (const float*)d_in[5];
    const float* gamma2 = (const float*)d_in[6];
    const float* beta2  = (const float*)d_in[7];
    float* y = (float*)d_out;

    float* ws   = (float*)d_ws;
    float* sum1 = ws;            float* sq1 = ws + 480;
    float* sum2 = ws + 960;      float* sq2 = ws + 1440;
    float* a1   = ws + 1920;     float* b1  = ws + 2400;
    float* a2   = ws + 2880;     float* b2  = ws + 3360;
    float* lcs  = ws + 3840;     // 5*64 = 320 (stride-64 padded)
    __bf16* W1b = (__bf16*)(ws + 4160);   // 30720 bf16
    __bf16* W2b = (__bf16*)(ws + 19520);  // 46080 bf16

    // zero sum1+sq1+sum2+sq2 (contiguous 1920 floats)
    hipMemsetAsync(ws, 0, 1920 * sizeof(float), stream);

    k_prep <<<305, 256, 0, stream>>>(W1, W2, L, W1b, W2b, lcs);
    k_stat1<<<dim3(64, G, B), 256, 0, stream>>>(x, W1b, sum1, sq1);
    k_fin  <<<2, 256, 0, stream>>>(sum1, sq1, gamma1, beta1, a1, b1);
    k_fused<<<dim3(64, G, B), 256, 0, stream>>>(x, W1b, W2b, a1, b1, (__bf16*)d_out, sum2, sq2);
    k_fin  <<<2, 256, 0, stream>>>(sum2, sq2, gamma2, beta2, a2, b2);
    k_adj  <<<dim3(COUT, B), 256, 0, stream>>>(y, L, a2, b2, lcs);
}